// Round 1
// baseline (275.628 us; speedup 1.0000x reference)
//
#include <hip/hip_runtime.h>

// GConvGRU (ChebConv K=1) + ReLU + Linear, fully fused.
// With H0 = 0:  Z = sigmoid(x@Wxz + bxz + bhz)
//               H_tilde = tanh(x@Wxh + bxh + bhh)      (R-gate cancels: R*H0 = 0)
//               out = relu((1-Z)*H_tilde) @ Wlin + blin
// edge_index / edge_weight are mathematically unused (K=1) -> never read (saves 320 MB).

constexpr int F = 16;   // F_IN
constexpr int HD = 32;  // HID

__global__ __launch_bounds__(256) void gconv_gru_fused(
    const float* __restrict__ x,
    const float* __restrict__ Wxz,
    const float* __restrict__ bxz,
    const float* __restrict__ bhz,
    const float* __restrict__ Wxh,
    const float* __restrict__ bxh,
    const float* __restrict__ bhh,
    const float* __restrict__ Wlin,
    const float* __restrict__ blin,
    float* __restrict__ out,
    int n)
{
    const int i = blockIdx.x * 256 + threadIdx.x;
    if (i >= n) return;

    // Load this node's 16 features as 4x float4 (rows are 64B-aligned).
    const float4* xp = reinterpret_cast<const float4*>(x + (size_t)i * F);
    float xs[F];
    #pragma unroll
    for (int q = 0; q < 4; ++q) {
        float4 v = xp[q];
        xs[4 * q + 0] = v.x;
        xs[4 * q + 1] = v.y;
        xs[4 * q + 2] = v.z;
        xs[4 * q + 3] = v.w;
    }

    // Weight pointers as float4; all indices below are compile-time constants
    // after unroll -> uniform (scalar) loads through the constant cache.
    const float4* wz = reinterpret_cast<const float4*>(Wxz);
    const float4* wh = reinterpret_cast<const float4*>(Wxh);

    float accZ[HD];
    float accH[HD];
    #pragma unroll
    for (int j = 0; j < HD; ++j) { accZ[j] = 0.f; accH[j] = 0.f; }

    #pragma unroll
    for (int k = 0; k < F; ++k) {
        const float xk = xs[k];
        #pragma unroll
        for (int j4 = 0; j4 < HD / 4; ++j4) {
            const float4 w = wz[k * (HD / 4) + j4];
            accZ[4 * j4 + 0] = fmaf(xk, w.x, accZ[4 * j4 + 0]);
            accZ[4 * j4 + 1] = fmaf(xk, w.y, accZ[4 * j4 + 1]);
            accZ[4 * j4 + 2] = fmaf(xk, w.z, accZ[4 * j4 + 2]);
            accZ[4 * j4 + 3] = fmaf(xk, w.w, accZ[4 * j4 + 3]);
            const float4 v = wh[k * (HD / 4) + j4];
            accH[4 * j4 + 0] = fmaf(xk, v.x, accH[4 * j4 + 0]);
            accH[4 * j4 + 1] = fmaf(xk, v.y, accH[4 * j4 + 1]);
            accH[4 * j4 + 2] = fmaf(xk, v.z, accH[4 * j4 + 2]);
            accH[4 * j4 + 3] = fmaf(xk, v.w, accH[4 * j4 + 3]);
        }
    }

    // Epilogue: gates + relu + final dot with Wlin.
    float res = blin[0];
    #pragma unroll
    for (int j = 0; j < HD; ++j) {
        const float az = accZ[j] + bxz[j] + bhz[j];
        const float ah = accH[j] + bxh[j] + bhh[j];
        // sigmoid(az) = 1 / (1 + e^-az); rcp(inf) = 0 -> saturates cleanly.
        const float z = __builtin_amdgcn_rcpf(1.f + __expf(-az));
        // tanh(ah) = 1 - 2/(e^(2ah) + 1); overflow-safe (-> +/-1 at extremes).
        const float th = 1.f - 2.f * __builtin_amdgcn_rcpf(1.f + __expf(2.f * ah));
        float hc = (1.f - z) * th;
        hc = fmaxf(hc, 0.f);
        res = fmaf(hc, Wlin[j], res);
    }
    out[i] = res;
}

extern "C" void kernel_launch(void* const* d_in, const int* in_sizes, int n_in,
                              void* d_out, int out_size, void* d_ws, size_t ws_size,
                              hipStream_t stream) {
    // setup_inputs order:
    // 0:x 1:edge_index 2:edge_weight 3:Wxz 4:bxz 5:Whz 6:bhz 7:Wxr 8:bxr
    // 9:Whr 10:bhr 11:Wxh 12:bxh 13:Whh 14:bhh 15:Wlin 16:blin
    const float* x    = (const float*)d_in[0];
    const float* Wxz  = (const float*)d_in[3];
    const float* bxz  = (const float*)d_in[4];
    const float* bhz  = (const float*)d_in[6];
    const float* Wxh  = (const float*)d_in[11];
    const float* bxh  = (const float*)d_in[12];
    const float* bhh  = (const float*)d_in[14];
    const float* Wlin = (const float*)d_in[15];
    const float* blin = (const float*)d_in[16];
    float* out = (float*)d_out;

    const int n = in_sizes[0] / F;  // 1,000,000 nodes
    const int blocks = (n + 255) / 256;
    gconv_gru_fused<<<blocks, 256, 0, stream>>>(
        x, Wxz, bxz, bhz, Wxh, bxh, bhh, Wlin, blin, out, n);
}

// Round 2
// 270.003 us; speedup vs baseline: 1.0208x; 1.0208x over previous
//
#include <hip/hip_runtime.h>

// GConvGRU (ChebConv K=1) + ReLU + Linear, fully fused, H0 = 0:
//   Z  = sigmoid(x@Wxz + bxz + bhz)
//   Ht = tanh(x@Wxh + bxh + bhh)          (R-gate cancels: R*H0 = 0)
//   out = relu((1-Z)*Ht) @ Wlin + blin
// edge_index / edge_weight mathematically unused (K=1) -> never read.
//
// R1 changes vs R0:
//  * 4 nodes/thread: weight-load instructions per node cut 4x (theory: L1-BW
//    bound on re-fetched weight vectors was the R0 bottleneck).
//  * node-pairs packed into float2 -> v_pk_fma_f32 (2 fp32 FMA/inst).
//  * biases folded into accumulator init.
//  * one-rcp epilogue: relu((1-Z)*tanh) = max(v-1,0) / ((1+u)(1+v)),
//    u = e^az, v = e^{2*ah}  (v clamped to stay finite).

typedef float v2f __attribute__((ext_vector_type(2)));

constexpr int F   = 16;  // F_IN
constexpr int HD  = 32;  // HID
constexpr int NPT = 4;   // nodes per thread
constexpr int JB  = 4;   // hidden-dim block per chunk

__global__ __launch_bounds__(256) void gru_fused(
    const float* __restrict__ x,
    const float* __restrict__ Wxz, const float* __restrict__ bxz,
    const float* __restrict__ bhz,
    const float* __restrict__ Wxh, const float* __restrict__ bxh,
    const float* __restrict__ bhh,
    const float* __restrict__ Wlin, const float* __restrict__ blin,
    float* __restrict__ out, int n)
{
    const int t = blockIdx.x * 256 + threadIdx.x;
    const int base = t * NPT;
    if (base >= n) return;  // n % 4 == 0, so whole-quad guard is exact

    // Load 4 nodes' features (16 floats each) as float4s; keep in registers.
    float xs[NPT][F];
    #pragma unroll
    for (int m = 0; m < NPT; ++m) {
        const float4* xp = reinterpret_cast<const float4*>(x + (size_t)(base + m) * F);
        #pragma unroll
        for (int q = 0; q < 4; ++q) {
            float4 v = xp[q];
            xs[m][4 * q + 0] = v.x;
            xs[m][4 * q + 1] = v.y;
            xs[m][4 * q + 2] = v.z;
            xs[m][4 * q + 3] = v.w;
        }
    }

    float res[NPT];
    #pragma unroll
    for (int m = 0; m < NPT; ++m) res[m] = blin[0];

    #pragma unroll 1  // keep code compact; ILP comes from 16 indep. pk-FMA chains
    for (int jb = 0; jb < HD / JB; ++jb) {
        // Accumulators: [j][node-pair] as float2 over pairs (0,1) and (2,3).
        v2f accZ[JB][NPT / 2];
        v2f accH[JB][NPT / 2];
        #pragma unroll
        for (int j = 0; j < JB; ++j) {
            const int jj = jb * JB + j;
            const float bz = bxz[jj] + bhz[jj];
            const float bh = bxh[jj] + bhh[jj];
            #pragma unroll
            for (int p = 0; p < NPT / 2; ++p) {
                v2f vz = {bz, bz};
                v2f vh = {bh, bh};
                accZ[j][p] = vz;
                accH[j][p] = vh;
            }
        }

        #pragma unroll
        for (int k = 0; k < F; ++k) {
            v2f xk[NPT / 2];
            #pragma unroll
            for (int p = 0; p < NPT / 2; ++p) {
                v2f v = {xs[2 * p][k], xs[2 * p + 1][k]};
                xk[p] = v;
            }
            #pragma unroll
            for (int j = 0; j < JB; ++j) {
                const int jj = jb * JB + j;
                const float wz = Wxz[k * HD + jj];  // uniform address -> s_load
                const float wh = Wxh[k * HD + jj];
                v2f wz2 = {wz, wz};
                v2f wh2 = {wh, wh};
                #pragma unroll
                for (int p = 0; p < NPT / 2; ++p) {
                    accZ[j][p] = __builtin_elementwise_fma(xk[p], wz2, accZ[j][p]);
                    accH[j][p] = __builtin_elementwise_fma(xk[p], wh2, accH[j][p]);
                }
            }
        }

        // Epilogue for this j-chunk.
        #pragma unroll
        for (int j = 0; j < JB; ++j) {
            const int jj = jb * JB + j;
            const float wl = Wlin[jj];
            #pragma unroll
            for (int p = 0; p < NPT / 2; ++p) {
                #pragma unroll
                for (int h = 0; h < 2; ++h) {
                    const float az = accZ[j][p][h];
                    const float ah = accH[j][p][h];
                    // u = e^az, v = e^{2ah} (clamped finite);
                    // relu((1-Z)*tanh) = max(v-1,0) * rcp((1+u)(1+v))
                    const float u = __expf(az);
                    const float v = __expf(fminf(2.f * ah, 87.f));
                    const float r = __builtin_amdgcn_rcpf((1.f + u) * (1.f + v));
                    const float num = fmaxf(v - 1.f, 0.f);
                    res[2 * p + h] = fmaf(num * r, wl, res[2 * p + h]);
                }
            }
        }
    }

    // 4 contiguous outputs per thread -> one dwordx4 store.
    float4 o = make_float4(res[0], res[1], res[2], res[3]);
    *reinterpret_cast<float4*>(out + base) = o;
}

extern "C" void kernel_launch(void* const* d_in, const int* in_sizes, int n_in,
                              void* d_out, int out_size, void* d_ws, size_t ws_size,
                              hipStream_t stream) {
    // setup_inputs order:
    // 0:x 1:edge_index 2:edge_weight 3:Wxz 4:bxz 5:Whz 6:bhz 7:Wxr 8:bxr
    // 9:Whr 10:bhr 11:Wxh 12:bxh 13:Whh 14:bhh 15:Wlin 16:blin
    const float* x    = (const float*)d_in[0];
    const float* Wxz  = (const float*)d_in[3];
    const float* bxz  = (const float*)d_in[4];
    const float* bhz  = (const float*)d_in[6];
    const float* Wxh  = (const float*)d_in[11];
    const float* bxh  = (const float*)d_in[12];
    const float* bhh  = (const float*)d_in[14];
    const float* Wlin = (const float*)d_in[15];
    const float* blin = (const float*)d_in[16];
    float* out = (float*)d_out;

    const int n = in_sizes[0] / F;          // 1,000,000 nodes
    const int threads = n / NPT;            // 250,000
    const int blocks = (threads + 255) / 256;
    gru_fused<<<blocks, 256, 0, stream>>>(
        x, Wxz, bxz, bhz, Wxh, bxh, bhh, Wlin, blin, out, n);
}